// Round 3
// baseline (157.548 us; speedup 1.0000x reference)
//
#include <hip/hip_runtime.h>

#define NBOX 8192

// ---------------------------------------------------------------- prep ------
// Clip boxes, compute validity + total-order key, zero d_out, reset counter.
// key = (hi(score) << 32) | index ; ascending key == descending prob, stable.
__global__ void prep_kernel(const float4* __restrict__ boxes,
                            const float* __restrict__ scores,
                            const int* __restrict__ ph, const int* __restrict__ pw,
                            unsigned long long* __restrict__ keys,
                            float4* __restrict__ xyxy, float4* __restrict__ cxcywh,
                            unsigned char* __restrict__ validb,
                            float4* __restrict__ out, int npro,
                            int* __restrict__ counter) {
#pragma clang fp contract(off)
    int i = blockIdx.x * blockDim.x + threadIdx.x;
    if (i == 0) *counter = 0;
    if (i >= NBOX) return;
    if (i < npro) out[i] = make_float4(0.f, 0.f, 0.f, 0.f);
    float xmax = (float)(*pw - 1);
    float ymax = (float)(*ph - 1);
    float4 b = boxes[i];                    // cx, cy, w, h
    float hw = 0.5f * b.z;
    float hh = 0.5f * b.w;
    float x1 = fminf(fmaxf(b.x - hw, 0.0f), xmax);
    float x2 = fminf(fmaxf(b.x + hw, 0.0f), xmax);
    float y1 = fminf(fmaxf(b.y - hh, 0.0f), ymax);
    float y2 = fminf(fmaxf(b.y + hh, 0.0f), ymax);
    float cw = x2 - x1, chh = y2 - y1;
    bool valid = (cw > 0.0f) && (chh > 0.0f);
    xyxy[i]   = make_float4(x1, y1, x2, y2);
    cxcywh[i] = make_float4(0.5f * (x1 + x2), 0.5f * (y1 + y2), cw, chh);
    validb[i] = valid ? 1 : 0;
    float s = scores[i];
    unsigned int sb  = __float_as_uint(s);
    unsigned int asc = (sb & 0x80000000u) ? ~sb : (sb | 0x80000000u);
    unsigned int hi  = valid ? ~asc : 0xFFFFFFFFu;   // smaller key = better
    keys[i] = ((unsigned long long)hi << 32) | (unsigned int)i;
}

// --------------------------------------------------------------- edges ------
// Unsorted lower-triangular 128x128 tiles; 256 threads = 128 rows x 2 lanes.
// For each overlapping pair, direction decided by key comparison:
// edge = (loser << 16) | winner.
__global__ __launch_bounds__(256)
void edge_kernel(const float4* __restrict__ xyxy,
                 const unsigned long long* __restrict__ keys,
                 unsigned int* __restrict__ edges, int* __restrict__ counter,
                 int ecap) {
#pragma clang fp contract(off)
    __shared__ float4 tj[128];
    __shared__ float  ta[128];
    __shared__ unsigned long long tk[128];
    int b = blockIdx.x;
    int bi = (int)((sqrtf(8.0f * (float)b + 1.0f) - 1.0f) * 0.5f);
    while ((bi + 1) * (bi + 2) / 2 <= b) ++bi;
    while (bi * (bi + 1) / 2 > b) --bi;
    int bj = b - bi * (bi + 1) / 2;
    int t = threadIdx.x;
    int ib = bi * 128, jb = bj * 128;
    if (t < 128) {
        float4 v = xyxy[jb + t];
        tj[t] = v;
        ta[t] = (v.z - v.x) * (v.w - v.y);
        tk[t] = keys[jb + t];
    }
    __syncthreads();
    int r = t >> 1, l = t & 1;
    int i = ib + r;
    float4 b4 = xyxy[i];
    float ai = (b4.z - b4.x) * (b4.w - b4.y);
    unsigned long long ki = keys[i];
    for (int jj = l; jj < 128; jj += 2) {
        int j = jb + jj;
        if (j >= i) break;                 // lower triangle by index
        float4 bj4 = tj[jj];
        float ix1 = fmaxf(b4.x, bj4.x);
        float iy1 = fmaxf(b4.y, bj4.y);
        float ix2 = fminf(b4.z, bj4.z);
        float iy2 = fminf(b4.w, bj4.w);
        float iw  = fmaxf(ix2 - ix1, 0.0f);
        float ih  = fmaxf(iy2 - iy1, 0.0f);
        float inter = iw * ih;
        float uni   = ai + ta[jj] - inter;
        float iou   = inter / fmaxf(uni, 1e-8f);
        if (iou > 0.7f) {
            unsigned long long kj = tk[jj];
            unsigned int loser, winner;
            if (ki < kj) { winner = (unsigned int)i; loser = (unsigned int)j; }
            else         { winner = (unsigned int)j; loser = (unsigned int)i; }
            int pos = atomicAdd(counter, 1);
            if (pos < ecap) edges[pos] = (loser << 16) | winner;
        }
    }
}

// -------------------------------------------------------------- resolve -----
// Fixpoint of kept[l] = valid[l] && !any(kept[w] : edge (l,w)). Unique
// solution (edges follow the strict key order => well-founded DAG).
__global__ __launch_bounds__(1024)
void resolve_kernel(const unsigned char* __restrict__ validg,
                    const unsigned int* __restrict__ edges,
                    const int* __restrict__ counter,
                    unsigned char* __restrict__ keptg, int ecap) {
    __shared__ unsigned char kept[NBOX];
    __shared__ unsigned char validb[NBOX];
    __shared__ unsigned char sup[NBOX];
    __shared__ int s_changed;
    int t = threadIdx.x;
    int E = *counter;
    if (E > ecap) E = ecap;
    for (int i = t; i < NBOX; i += 1024) {
        unsigned char v = validg[i];
        validb[i] = v;
        kept[i] = v;
    }
    __syncthreads();
    for (int iter = 0; iter < NBOX; ++iter) {
        for (int i = t; i < NBOX; i += 1024) sup[i] = 0;
        if (t == 0) s_changed = 0;
        __syncthreads();
        for (int e = t; e < E; e += 1024) {
            unsigned int ed = edges[e];
            int l = (int)(ed >> 16), w = (int)(ed & 0xFFFFu);
            if (kept[w]) sup[l] = 1;
        }
        __syncthreads();
        int changed = 0;
        for (int i = t; i < NBOX; i += 1024) {
            unsigned char nk = (unsigned char)(validb[i] && !sup[i]);
            if (nk != kept[i]) { kept[i] = nk; changed = 1; }
        }
        if (changed) s_changed = 1;
        __syncthreads();
        int done = (s_changed == 0);
        __syncthreads();
        if (done) break;
    }
    for (int i = t; i < NBOX; i += 1024) keptg[i] = kept[i];
}

// --------------------------------------------------------- rank+scatter -----
// rank[i] = #{ j : kept[j] && key[j] < key[i] }; kept[i] && rank < npro
// -> out[rank] = cxcywh[i]. Keys unique => ranks unique => exact top_k order.
// 256 blocks x 256 threads = 32 rows/block x 8 lanes; j tiled in LDS.
#define RANK_TILE 2048
__global__ __launch_bounds__(256)
void rank_scatter_kernel(const unsigned long long* __restrict__ keys,
                         const unsigned char* __restrict__ keptg,
                         const float4* __restrict__ cxcywh,
                         float4* __restrict__ out, int npro) {
    __shared__ unsigned long long tk[RANK_TILE];
    __shared__ unsigned char tkept[RANK_TILE];
    int t = threadIdx.x;
    int row = blockIdx.x * 32 + (t >> 3);
    int lane = t & 7;
    unsigned long long ki = keys[row];
    int partial = 0;
    for (int j0 = 0; j0 < NBOX; j0 += RANK_TILE) {
        for (int j = t; j < RANK_TILE; j += 256) {
            tk[j] = keys[j0 + j];
            tkept[j] = keptg[j0 + j];
        }
        __syncthreads();
        for (int j = lane; j < RANK_TILE; j += 8) {
            partial += (tkept[j] && (tk[j] < ki)) ? 1 : 0;
        }
        __syncthreads();
    }
    // reduce 8 lanes (contiguous threads, same wave)
    partial += __shfl_down(partial, 4, 8);
    partial += __shfl_down(partial, 2, 8);
    partial += __shfl_down(partial, 1, 8);
    if (lane == 0) {
        if (keptg[row] && partial < npro) out[partial] = cxcywh[row];
    }
}

// --------------------------------------------------------------- host -------
extern "C" void kernel_launch(void* const* d_in, const int* in_sizes, int n_in,
                              void* d_out, int out_size, void* d_ws, size_t ws_size,
                              hipStream_t stream) {
    const float4* boxes  = (const float4*)d_in[0];
    const float* scores  = (const float*)d_in[1];
    const int* ph        = (const int*)d_in[2];
    const int* pw        = (const int*)d_in[3];

    char* ws = (char*)d_ws;
    size_t off = 0;
    unsigned long long* keys = (unsigned long long*)(ws + off); off += (size_t)NBOX * 8;
    float4* xyxy     = (float4*)(ws + off); off += (size_t)NBOX * 16;
    float4* cxcywh   = (float4*)(ws + off); off += (size_t)NBOX * 16;
    unsigned char* validb = (unsigned char*)(ws + off); off += NBOX;
    unsigned char* keptg  = (unsigned char*)(ws + off); off += NBOX;
    off = (off + 63) & ~(size_t)63;
    int* counter = (int*)(ws + off); off += 64;
    unsigned int* edges = (unsigned int*)(ws + off);

    int ecap = 262144;
    if (ws_size > off) {
        size_t room = (ws_size - off) / 4;
        if ((size_t)ecap > room) ecap = (int)room;
    } else {
        ecap = 0;
    }
    int npro = out_size / 4;

    prep_kernel<<<NBOX / 256, 256, 0, stream>>>(boxes, scores, ph, pw, keys, xyxy,
                                                cxcywh, validb, (float4*)d_out, npro,
                                                counter);
    int ntiles = NBOX / 128;                                   // 64
    edge_kernel<<<ntiles * (ntiles + 1) / 2, 256, 0, stream>>>(xyxy, keys, edges,
                                                               counter, ecap);
    resolve_kernel<<<1, 1024, 0, stream>>>(validb, edges, counter, keptg, ecap);
    rank_scatter_kernel<<<NBOX / 32, 256, 0, stream>>>(keys, keptg, cxcywh,
                                                       (float4*)d_out, npro);
}

// Round 4
// 63.818 us; speedup vs baseline: 2.4687x; 2.4687x over previous
//
#include <hip/hip_runtime.h>

#define NBOX 8192

// ---------------------------------------------------------------- prep ------
// Clip boxes, validity, total-order key; zero d_out + rank; reset counter.
// key = (hi(score) << 32) | index ; ascending key == descending prob, stable.
__global__ void prep_kernel(const float4* __restrict__ boxes,
                            const float* __restrict__ scores,
                            const int* __restrict__ ph, const int* __restrict__ pw,
                            unsigned long long* __restrict__ keys,
                            float4* __restrict__ xyxy, float4* __restrict__ cxcywh,
                            unsigned char* __restrict__ validb,
                            int* __restrict__ rank,
                            float4* __restrict__ out, int npro,
                            int* __restrict__ counter) {
#pragma clang fp contract(off)
    int i = blockIdx.x * blockDim.x + threadIdx.x;
    if (i == 0) *counter = 0;
    if (i >= NBOX) return;
    if (i < npro) out[i] = make_float4(0.f, 0.f, 0.f, 0.f);
    rank[i] = 0;
    float xmax = (float)(*pw - 1);
    float ymax = (float)(*ph - 1);
    float4 b = boxes[i];                    // cx, cy, w, h
    float hw = 0.5f * b.z;
    float hh = 0.5f * b.w;
    float x1 = fminf(fmaxf(b.x - hw, 0.0f), xmax);
    float x2 = fminf(fmaxf(b.x + hw, 0.0f), xmax);
    float y1 = fminf(fmaxf(b.y - hh, 0.0f), ymax);
    float y2 = fminf(fmaxf(b.y + hh, 0.0f), ymax);
    float cw = x2 - x1, chh = y2 - y1;
    bool valid = (cw > 0.0f) && (chh > 0.0f);
    xyxy[i]   = make_float4(x1, y1, x2, y2);
    cxcywh[i] = make_float4(0.5f * (x1 + x2), 0.5f * (y1 + y2), cw, chh);
    validb[i] = valid ? 1 : 0;
    float s = scores[i];
    unsigned int sb  = __float_as_uint(s);
    unsigned int asc = (sb & 0x80000000u) ? ~sb : (sb | 0x80000000u);
    unsigned int hi  = valid ? ~asc : 0xFFFFFFFFu;   // smaller key = better
    keys[i] = ((unsigned long long)hi << 32) | (unsigned int)i;
}

// --------------------------------------------------------------- edges ------
// Unsorted lower-triangular 128x128 tiles; 256 threads = 128 rows x 2 lanes.
// For each overlapping pair, direction by key comparison:
// edge = (loser << 16) | winner.
__global__ __launch_bounds__(256)
void edge_kernel(const float4* __restrict__ xyxy,
                 const unsigned long long* __restrict__ keys,
                 unsigned int* __restrict__ edges, int* __restrict__ counter,
                 int ecap) {
#pragma clang fp contract(off)
    __shared__ float4 tj[128];
    __shared__ float  ta[128];
    __shared__ unsigned long long tk[128];
    int b = blockIdx.x;
    int bi = (int)((sqrtf(8.0f * (float)b + 1.0f) - 1.0f) * 0.5f);
    while ((bi + 1) * (bi + 2) / 2 <= b) ++bi;
    while (bi * (bi + 1) / 2 > b) --bi;
    int bj = b - bi * (bi + 1) / 2;
    int t = threadIdx.x;
    int ib = bi * 128, jb = bj * 128;
    if (t < 128) {
        float4 v = xyxy[jb + t];
        tj[t] = v;
        ta[t] = (v.z - v.x) * (v.w - v.y);
        tk[t] = keys[jb + t];
    }
    __syncthreads();
    int r = t >> 1, l = t & 1;
    int i = ib + r;
    float4 b4 = xyxy[i];
    float ai = (b4.z - b4.x) * (b4.w - b4.y);
    unsigned long long ki = keys[i];
    for (int jj = l; jj < 128; jj += 2) {
        int j = jb + jj;
        if (j >= i) break;                 // lower triangle by index
        float4 bj4 = tj[jj];
        float ix1 = fmaxf(b4.x, bj4.x);
        float iy1 = fmaxf(b4.y, bj4.y);
        float ix2 = fminf(b4.z, bj4.z);
        float iy2 = fminf(b4.w, bj4.w);
        float iw  = fmaxf(ix2 - ix1, 0.0f);
        float ih  = fmaxf(iy2 - iy1, 0.0f);
        float inter = iw * ih;
        float uni   = ai + ta[jj] - inter;
        float iou   = inter / fmaxf(uni, 1e-8f);
        if (iou > 0.7f) {
            unsigned long long kj = tk[jj];
            unsigned int loser, winner;
            if (ki < kj) { winner = (unsigned int)i; loser = (unsigned int)j; }
            else         { winner = (unsigned int)j; loser = (unsigned int)i; }
            int pos = atomicAdd(counter, 1);
            if (pos < ecap) edges[pos] = (loser << 16) | winner;
        }
    }
}

// -------------------------------------------------------------- resolve -----
// Fixpoint of kept[l] = valid[l] && !any(kept[w] : edge (l,w)); unique
// (edges follow strict key order => well-founded DAG). Emits kept bytes and
// rkeys[i] = kept ? key : ~0 (so rank's inner loop is one u64 compare).
__global__ __launch_bounds__(1024)
void resolve_kernel(const unsigned char* __restrict__ validg,
                    const unsigned int* __restrict__ edges,
                    const int* __restrict__ counter,
                    const unsigned long long* __restrict__ keys,
                    unsigned char* __restrict__ keptg,
                    unsigned long long* __restrict__ rkeys, int ecap) {
    __shared__ unsigned char kept[NBOX];
    __shared__ unsigned char validb[NBOX];
    __shared__ unsigned char sup[NBOX];
    __shared__ int s_changed;
    int t = threadIdx.x;
    int E = *counter;
    if (E > ecap) E = ecap;
    for (int i = t; i < NBOX; i += 1024) {
        unsigned char v = validg[i];
        validb[i] = v;
        kept[i] = v;
    }
    __syncthreads();
    for (int iter = 0; iter < NBOX; ++iter) {
        for (int i = t; i < NBOX; i += 1024) sup[i] = 0;
        if (t == 0) s_changed = 0;
        __syncthreads();
        for (int e = t; e < E; e += 1024) {
            unsigned int ed = edges[e];
            int l = (int)(ed >> 16), w = (int)(ed & 0xFFFFu);
            if (kept[w]) sup[l] = 1;
        }
        __syncthreads();
        int changed = 0;
        for (int i = t; i < NBOX; i += 1024) {
            unsigned char nk = (unsigned char)(validb[i] && !sup[i]);
            if (nk != kept[i]) { kept[i] = nk; changed = 1; }
        }
        if (changed) s_changed = 1;
        __syncthreads();
        int done = (s_changed == 0);
        __syncthreads();
        if (done) break;
    }
    for (int i = t; i < NBOX; i += 1024) {
        unsigned char k = kept[i];
        keptg[i] = k;
        rkeys[i] = k ? keys[i] : ~0ull;
    }
}

// ----------------------------------------------------------------- rank -----
// rank[i] += #{ j in chunk : rkeys[j] < rkeys_like_key[i] } over 8 j-chunks.
// Grid = 2048 blocks (chunk = bid>>8, rowgroup = bid&255); 256 thr =
// 32 rows x 8 lanes; 1024-key chunk staged in LDS; full occupancy.
#define RCHUNK 1024
__global__ __launch_bounds__(256)
void rank_partial_kernel(const unsigned long long* __restrict__ keys,
                         const unsigned long long* __restrict__ rkeys,
                         int* __restrict__ rank) {
    __shared__ unsigned long long tk[RCHUNK];
    int t = threadIdx.x;
    int chunk = blockIdx.x >> 8;
    int rowg  = blockIdx.x & 255;
    int jbase = chunk * RCHUNK;
#pragma unroll
    for (int m = 0; m < RCHUNK / 256; ++m) tk[t + m * 256] = rkeys[jbase + t + m * 256];
    __syncthreads();
    int row = rowg * 32 + (t >> 3);
    int lane = t & 7;
    unsigned long long ki = keys[row];
    int partial = 0;
#pragma unroll 16
    for (int j = lane; j < RCHUNK; j += 8) partial += (tk[j] < ki) ? 1 : 0;
    partial += __shfl_down(partial, 4, 8);
    partial += __shfl_down(partial, 2, 8);
    partial += __shfl_down(partial, 1, 8);
    if (lane == 0 && partial) atomicAdd(&rank[row], partial);
}

// -------------------------------------------------------------- scatter -----
__global__ void scatter_kernel(const unsigned char* __restrict__ keptg,
                               const int* __restrict__ rank,
                               const float4* __restrict__ cxcywh,
                               float4* __restrict__ out, int npro) {
    int i = blockIdx.x * blockDim.x + threadIdx.x;
    if (i >= NBOX) return;
    if (keptg[i]) {
        int r = rank[i];
        if (r < npro) out[r] = cxcywh[i];
    }
}

// --------------------------------------------------------------- host -------
extern "C" void kernel_launch(void* const* d_in, const int* in_sizes, int n_in,
                              void* d_out, int out_size, void* d_ws, size_t ws_size,
                              hipStream_t stream) {
    const float4* boxes  = (const float4*)d_in[0];
    const float* scores  = (const float*)d_in[1];
    const int* ph        = (const int*)d_in[2];
    const int* pw        = (const int*)d_in[3];

    char* ws = (char*)d_ws;
    size_t off = 0;
    unsigned long long* keys  = (unsigned long long*)(ws + off); off += (size_t)NBOX * 8;
    unsigned long long* rkeys = (unsigned long long*)(ws + off); off += (size_t)NBOX * 8;
    float4* xyxy     = (float4*)(ws + off); off += (size_t)NBOX * 16;
    float4* cxcywh   = (float4*)(ws + off); off += (size_t)NBOX * 16;
    int* rank        = (int*)(ws + off);    off += (size_t)NBOX * 4;
    unsigned char* validb = (unsigned char*)(ws + off); off += NBOX;
    unsigned char* keptg  = (unsigned char*)(ws + off); off += NBOX;
    off = (off + 63) & ~(size_t)63;
    int* counter = (int*)(ws + off); off += 64;
    unsigned int* edges = (unsigned int*)(ws + off);

    int ecap = 262144;
    if (ws_size > off) {
        size_t room = (ws_size - off) / 4;
        if ((size_t)ecap > room) ecap = (int)room;
    } else {
        ecap = 0;
    }
    int npro = out_size / 4;

    prep_kernel<<<NBOX / 256, 256, 0, stream>>>(boxes, scores, ph, pw, keys, xyxy,
                                                cxcywh, validb, rank,
                                                (float4*)d_out, npro, counter);
    int ntiles = NBOX / 128;                                   // 64
    edge_kernel<<<ntiles * (ntiles + 1) / 2, 256, 0, stream>>>(xyxy, keys, edges,
                                                               counter, ecap);
    resolve_kernel<<<1, 1024, 0, stream>>>(validb, edges, counter, keys, keptg,
                                           rkeys, ecap);
    rank_partial_kernel<<<(NBOX / 32) * (NBOX / RCHUNK), 256, 0, stream>>>(keys, rkeys, rank);
    scatter_kernel<<<NBOX / 256, 256, 0, stream>>>(keptg, rank, cxcywh,
                                                   (float4*)d_out, npro);
}